// Round 4
// baseline (3766.413 us; speedup 1.0000x reference)
//
#include <hip/hip_runtime.h>
#include <math.h>

#define NN 100000
#define NE 3200000
#define FIN 256
#define HH 128
#define CC 64
#define NL 16
#define NBLK 391  // ceil(NN/256)

typedef unsigned short u16;
typedef unsigned int u32;
typedef short short8 __attribute__((ext_vector_type(8)));
typedef float f32x4 __attribute__((ext_vector_type(4)));
typedef float float8 __attribute__((ext_vector_type(8)));

__device__ __forceinline__ float bf2f(u16 u) {
    u32 v = ((u32)u) << 16;
    return __builtin_bit_cast(float, v);
}
__device__ __forceinline__ u16 f2bf(float f) {
    u32 x = __builtin_bit_cast(u32, f);
    u32 lsb = (x >> 16) & 1;
    x += 0x7fffu + lsb;
    return (u16)(x >> 16);
}
__device__ __forceinline__ u32 pack2(float a, float b) {
    return (u32)f2bf(a) | ((u32)f2bf(b) << 16);
}

// ---------------- CSR build ----------------

__global__ void hist_kernel(const int* __restrict__ edst, int* __restrict__ counts,
                            int* __restrict__ rank) {
    int e = blockIdx.x * blockDim.x + threadIdx.x;
    if (e < NE) rank[e] = atomicAdd(&counts[edst[e]], 1);
}

// hierarchical scan: A = per-256-block inclusive scan, B = scan of block sums, C = combine
__global__ __launch_bounds__(256) void scanA_kernel(const int* __restrict__ counts,
                                                    int* __restrict__ incl, int* __restrict__ bsum) {
    __shared__ int s[256];
    int t = threadIdx.x, i = blockIdx.x * 256 + t;
    s[t] = (i < NN) ? counts[i] : 0;
    __syncthreads();
    for (int off = 1; off < 256; off <<= 1) {
        int v = (t >= off) ? s[t - off] : 0;
        __syncthreads();
        s[t] += v;
        __syncthreads();
    }
    if (i < NN) incl[i] = s[t];
    if (t == 255) bsum[blockIdx.x] = s[255];
}

__global__ __launch_bounds__(512) void scanB_kernel(int* __restrict__ bsum) {
    __shared__ int s[512];
    int t = threadIdx.x;
    s[t] = (t < NBLK) ? bsum[t] : 0;
    __syncthreads();
    for (int off = 1; off < 512; off <<= 1) {
        int v = (t >= off) ? s[t - off] : 0;
        __syncthreads();
        s[t] += v;
        __syncthreads();
    }
    if (t < NBLK) bsum[t] = s[t];
}

__global__ __launch_bounds__(256) void scanC_kernel(const int* __restrict__ counts,
                                                    const int* __restrict__ incl,
                                                    const int* __restrict__ bsum,
                                                    int* __restrict__ row_start) {
    int t = threadIdx.x, b = blockIdx.x, i = b * 256 + t;
    if (i < NN) row_start[i] = (b ? bsum[b - 1] : 0) + incl[i] - counts[i];
    if (i == 0) row_start[NN] = NE;
}

__global__ void scatter_kernel(const int* __restrict__ esrc, const int* __restrict__ edst,
                               const float* __restrict__ ew, const int* __restrict__ row_start,
                               const int* __restrict__ rank, int2* __restrict__ csr) {
    int e = blockIdx.x * blockDim.x + threadIdx.x;
    if (e < NE) {
        int d = edst[e];
        int pos = row_start[d] + rank[e];
        csr[pos] = make_int2(esrc[e], __builtin_bit_cast(int, ew[e]));
    }
}

// ---------------- weight fragment prep (see R3 layout comment) ----------------

__global__ void prep_kernel(const float* __restrict__ W0, const float* __restrict__ W1,
                            const float* __restrict__ CW, u16* __restrict__ Wfrag) {
    int f = blockIdx.x;
    int lane = threadIdx.x;  // 64
    const float* Wsrc;
    int KB, N, fl;
    float beta = -1.f;
    if (f < 64) { Wsrc = W0; KB = 8; N = 128; fl = f; }
    else if (f < 576) {
        int l = (f - 64) >> 5; fl = (f - 64) & 31;
        Wsrc = CW + (size_t)l * HH * HH; KB = 4; N = 128;
        beta = logf(0.5f / (float)(l + 1) + 1.0f);
    } else { Wsrc = W1; KB = 4; N = 64; fl = f - 576; }
    int j = fl / KB, k0 = fl % KB;
    int n = j * 16 + (lane & 15);
    u16* dst = Wfrag + (size_t)f * 512 + lane * 8;
#pragma unroll
    for (int i = 0; i < 8; ++i) {
        int k = k0 * 32 + ((lane >> 4) << 3) + i;
        float v = Wsrc[(size_t)k * N + n];
        if (beta >= 0.f) v = beta * v + ((k == n) ? (1.f - beta) : 0.f);
        dst[i] = f2bf(v);
    }
}

// ---------------- lin0: x = relu(X @ W0 + b0) -> xcur, x0 (bf16) ----------------

__global__ __launch_bounds__(256) void lin0_kernel(const float* __restrict__ X,
                                                   const u16* __restrict__ wf,
                                                   const float* __restrict__ B0,
                                                   u16* __restrict__ xcur,
                                                   u16* __restrict__ x0) {
    int lane = threadIdx.x & 63, w = threadIdx.x >> 6;
    int mb = (blockIdx.x * 4 + w) * 16;
    int r = lane & 15, g = lane >> 4;
    int arow = mb + r; if (arow >= NN) arow = NN - 1;
    const float* aprow = X + (size_t)arow * FIN + g * 8;
    const short8* bp = (const short8*)wf + lane;
    f32x4 acc[8] = {};
#pragma unroll
    for (int k0 = 0; k0 < 8; ++k0) {
        float8 af = *(const float8*)(aprow + k0 * 32);
        short8 a;
#pragma unroll
        for (int i = 0; i < 8; ++i) a[i] = (short)f2bf(af[i]);
#pragma unroll
        for (int j = 0; j < 8; ++j)
            acc[j] = __builtin_amdgcn_mfma_f32_16x16x32_bf16(a, bp[(j * 8 + k0) * 64], acc[j], 0, 0, 0);
    }
#pragma unroll
    for (int j = 0; j < 8; ++j) {
        int col = j * 16 + r;
        float b = B0[col];
#pragma unroll
        for (int reg = 0; reg < 4; ++reg) {
            int row = mb + g * 4 + reg;
            if (row < NN) {
                size_t idx = (size_t)row * HH + col;
                u16 v = f2bf(fmaxf(acc[j][reg] + b, 0.f));
                xcur[idx] = v;
                x0[idx] = v;
            }
        }
    }
}

// ---------------- fused layer: xout = relu( [0.9*SpMM(xin) + 0.1*x0] @ W' + xin ) ----------------
// 64 nodes/block. Phase 1: wave w aggregates nodes [w*16, w*16+16) (one wave per node,
// lane owns bf16 feature pair), stores mixed h row to swizzled LDS as bf16.
// Phase 2: wave w MFMAs its own 16-row tile (A from LDS, B = prepped W' frags).
// LDS swizzle: u16 index ^= (row&7)<<3 (byte ^= (row&7)<<4) on both write and read
// -> 2-way banks (free), b128 16B alignment preserved.

__global__ __launch_bounds__(256) void fused_kernel(const u16* __restrict__ xin,
                                                    const u16* __restrict__ x0,
                                                    const int2* __restrict__ csr,
                                                    const int* __restrict__ row_start,
                                                    const u16* __restrict__ wf,
                                                    u16* __restrict__ xout) {
    __shared__ u16 hlds[64 * 128];  // 16 KB
    int t = threadIdx.x, w = t >> 6, lane = t & 63;
    int nb = blockIdx.x * 64;
    const u32* xg = (const u32*)xin;
    const u32* x0g = (const u32*)x0;

    // phase 1: gather + residual mix
    for (int i = 0; i < 16; ++i) {
        int row = w * 16 + i;
        int node = nb + row;
        float a0 = 0.f, a1 = 0.f;
        if (node < NN) {
            int p = row_start[node], pe = row_start[node + 1];
            for (; p + 8 <= pe; p += 8) {
                int2 m[8];
#pragma unroll
                for (int q = 0; q < 8; ++q) m[q] = csr[p + q];
                u32 v[8];
#pragma unroll
                for (int q = 0; q < 8; ++q) v[q] = xg[(size_t)m[q].x * 64 + lane];
#pragma unroll
                for (int q = 0; q < 8; ++q) {
                    float wt = __builtin_bit_cast(float, m[q].y);
                    a0 += wt * bf2f((u16)v[q]);
                    a1 += wt * bf2f((u16)(v[q] >> 16));
                }
            }
            for (; p < pe; ++p) {
                int2 m = csr[p];
                float wt = __builtin_bit_cast(float, m.y);
                u32 v = xg[(size_t)m.x * 64 + lane];
                a0 += wt * bf2f((u16)v);
                a1 += wt * bf2f((u16)(v >> 16));
            }
            u32 xv = x0g[node * 64 + lane];
            a0 = 0.9f * a0 + 0.1f * bf2f((u16)xv);
            a1 = 0.9f * a1 + 0.1f * bf2f((u16)(xv >> 16));
        }
        u32 idx = (u32)(row * 128 + lane * 2) ^ (u32)((row & 7) << 3);
        *(u32*)&hlds[idx] = pack2(a0, a1);
    }
    __syncthreads();

    // phase 2: 16x128 MFMA tile per wave
    int r = lane & 15, g = lane >> 4;
    const short8* bp = (const short8*)wf + lane;
    f32x4 acc[8] = {};
#pragma unroll
    for (int kb = 0; kb < 4; ++kb) {
        u32 idx = (u32)((w * 16 + r) * 128 + kb * 32 + g * 8) ^ (u32)((r & 7) << 3);
        short8 a = *(const short8*)&hlds[idx];
#pragma unroll
        for (int j = 0; j < 8; ++j)
            acc[j] = __builtin_amdgcn_mfma_f32_16x16x32_bf16(a, bp[(j * 4 + kb) * 64], acc[j], 0, 0, 0);
    }
#pragma unroll
    for (int j = 0; j < 8; ++j) {
        int col = j * 16 + r;
#pragma unroll
        for (int reg = 0; reg < 4; ++reg) {
            int row = nb + w * 16 + g * 4 + reg;
            if (row < NN) {
                size_t idx = (size_t)row * HH + col;
                float v = acc[j][reg] + bf2f(xin[idx]);
                xout[idx] = f2bf(fmaxf(v, 0.f));
            }
        }
    }
}

// ---------------- lin1: out = x @ W1 + b1 (fp32 out) ----------------

__global__ __launch_bounds__(256) void lin1_kernel(const u16* __restrict__ x,
                                                   const u16* __restrict__ wf,
                                                   const float* __restrict__ B1,
                                                   float* __restrict__ out) {
    int lane = threadIdx.x & 63, w = threadIdx.x >> 6;
    int mb = (blockIdx.x * 4 + w) * 16;
    int r = lane & 15, g = lane >> 4;
    int arow = mb + r; if (arow >= NN) arow = NN - 1;
    const short8* ap = (const short8*)(x + (size_t)arow * HH) + g;
    const short8* bp = (const short8*)wf + lane;
    f32x4 acc[4] = {};
#pragma unroll
    for (int k0 = 0; k0 < 4; ++k0) {
        short8 a = ap[k0 * 4];
#pragma unroll
        for (int j = 0; j < 4; ++j)
            acc[j] = __builtin_amdgcn_mfma_f32_16x16x32_bf16(a, bp[(j * 4 + k0) * 64], acc[j], 0, 0, 0);
    }
#pragma unroll
    for (int j = 0; j < 4; ++j) {
        int col = j * 16 + r;
        float b = B1[col];
#pragma unroll
        for (int reg = 0; reg < 4; ++reg) {
            int row = mb + g * 4 + reg;
            if (row < NN) out[(size_t)row * CC + col] = acc[j][reg] + b;
        }
    }
}

// ---------------- host ----------------

extern "C" void kernel_launch(void* const* d_in, const int* in_sizes, int n_in,
                              void* d_out, int out_size, void* d_ws, size_t ws_size,
                              hipStream_t stream) {
    const float* X  = (const float*)d_in[0];
    const int* esrc = (const int*)d_in[1];
    const int* edst = (const int*)d_in[2];
    const float* ew = (const float*)d_in[3];
    const float* W0 = (const float*)d_in[4];
    const float* B0 = (const float*)d_in[5];
    const float* W1 = (const float*)d_in[6];
    const float* B1 = (const float*)d_in[7];
    const float* CW = (const float*)d_in[8];
    float* out = (float*)d_out;

    char* p = (char*)d_ws;
    auto alloc = [&](size_t bytes) {
        char* r = p;
        p += (bytes + 255) & ~(size_t)255;
        return r;
    };
    u16*  xbuf0     = (u16*)alloc((size_t)NN * HH * 2);
    u16*  xbuf1     = (u16*)alloc((size_t)NN * HH * 2);
    u16*  x0        = (u16*)alloc((size_t)NN * HH * 2);
    int*  row_start = (int*)alloc((size_t)(NN + 1) * 4);
    int*  counts    = (int*)alloc((size_t)NN * 4);
    int*  incl      = (int*)alloc((size_t)NN * 4);
    int*  bsum      = (int*)alloc((size_t)512 * 4);
    int*  rank      = (int*)alloc((size_t)NE * 4);
    int2* csr       = (int2*)alloc((size_t)NE * 8);
    u16*  Wfrag     = (u16*)alloc((size_t)592 * 512 * 2);

    hipMemsetAsync(counts, 0, (size_t)NN * 4, stream);
    hist_kernel<<<NE / 256, 256, 0, stream>>>(edst, counts, rank);
    scanA_kernel<<<NBLK, 256, 0, stream>>>(counts, incl, bsum);
    scanB_kernel<<<1, 512, 0, stream>>>(bsum);
    scanC_kernel<<<NBLK, 256, 0, stream>>>(counts, incl, bsum, row_start);
    scatter_kernel<<<NE / 256, 256, 0, stream>>>(esrc, edst, ew, row_start, rank, csr);
    prep_kernel<<<592, 64, 0, stream>>>(W0, W1, CW, Wfrag);

    const int gemm_blocks = (NN + 63) / 64;
    lin0_kernel<<<gemm_blocks, 256, 0, stream>>>(X, Wfrag, B0, xbuf0, x0);

    u16* bufs[2] = { xbuf0, xbuf1 };
    for (int l = 0; l < NL; ++l) {
        fused_kernel<<<gemm_blocks, 256, 0, stream>>>(bufs[l & 1], x0, csr, row_start,
                                                      Wfrag + (size_t)(64 + 32 * l) * 512,
                                                      bufs[(l + 1) & 1]);
    }

    lin1_kernel<<<gemm_blocks, 256, 0, stream>>>(bufs[0], Wfrag + (size_t)576 * 512, B1, out);
}

// Round 5
// 2457.209 us; speedup vs baseline: 1.5328x; 1.5328x over previous
//
#include <hip/hip_runtime.h>
#include <math.h>

#define NN 100000
#define NE 3200000
#define FIN 256
#define HH 128
#define CC 64
#define NL 16
#define NBLK 391  // ceil(NN/256)

typedef unsigned short u16;
typedef unsigned int u32;
typedef short short8 __attribute__((ext_vector_type(8)));
typedef float f32x4 __attribute__((ext_vector_type(4)));
typedef float float8 __attribute__((ext_vector_type(8)));

__device__ __forceinline__ float bf2f(u16 u) {
    u32 v = ((u32)u) << 16;
    return __builtin_bit_cast(float, v);
}
__device__ __forceinline__ u16 f2bf(float f) {
    u32 x = __builtin_bit_cast(u32, f);
    u32 lsb = (x >> 16) & 1;
    x += 0x7fffu + lsb;
    return (u16)(x >> 16);
}
__device__ __forceinline__ u32 pack2(float a, float b) {
    return (u32)f2bf(a) | ((u32)f2bf(b) << 16);
}

// ---------------- CSR build ----------------

__global__ void hist_kernel(const int* __restrict__ edst, int* __restrict__ counts,
                            int* __restrict__ rank) {
    int e = blockIdx.x * blockDim.x + threadIdx.x;
    if (e < NE) rank[e] = atomicAdd(&counts[edst[e]], 1);
}

// hierarchical scan: A = per-256-block inclusive scan, B = scan of block sums, C = combine
__global__ __launch_bounds__(256) void scanA_kernel(const int* __restrict__ counts,
                                                    int* __restrict__ incl, int* __restrict__ bsum) {
    __shared__ int s[256];
    int t = threadIdx.x, i = blockIdx.x * 256 + t;
    s[t] = (i < NN) ? counts[i] : 0;
    __syncthreads();
    for (int off = 1; off < 256; off <<= 1) {
        int v = (t >= off) ? s[t - off] : 0;
        __syncthreads();
        s[t] += v;
        __syncthreads();
    }
    if (i < NN) incl[i] = s[t];
    if (t == 255) bsum[blockIdx.x] = s[255];
}

__global__ __launch_bounds__(512) void scanB_kernel(int* __restrict__ bsum) {
    __shared__ int s[512];
    int t = threadIdx.x;
    s[t] = (t < NBLK) ? bsum[t] : 0;
    __syncthreads();
    for (int off = 1; off < 512; off <<= 1) {
        int v = (t >= off) ? s[t - off] : 0;
        __syncthreads();
        s[t] += v;
        __syncthreads();
    }
    if (t < NBLK) bsum[t] = s[t];
}

__global__ __launch_bounds__(256) void scanC_kernel(const int* __restrict__ counts,
                                                    const int* __restrict__ incl,
                                                    const int* __restrict__ bsum,
                                                    int* __restrict__ row_start) {
    int t = threadIdx.x, b = blockIdx.x, i = b * 256 + t;
    if (i < NN) row_start[i] = (b ? bsum[b - 1] : 0) + incl[i] - counts[i];
    if (i == 0) row_start[NN] = NE;
}

// packed edge: u32 = (src << 15) | round(w * 32 * 32767); w in [0, 1/32)
__global__ void scatter_kernel(const int* __restrict__ esrc, const int* __restrict__ edst,
                               const float* __restrict__ ew, const int* __restrict__ row_start,
                               const int* __restrict__ rank, u32* __restrict__ csr) {
    int e = blockIdx.x * blockDim.x + threadIdx.x;
    if (e < NE) {
        int d = edst[e];
        int pos = row_start[d] + rank[e];
        u32 wq = (u32)(ew[e] * 1048544.0f + 0.5f);
        if (wq > 32767u) wq = 32767u;
        csr[pos] = ((u32)esrc[e] << 15) | wq;
    }
}

// ---------------- weight fragment prep ----------------
// Fragment f of a weight set [K x N]: lane holds 8 contiguous bf16 =
// W[k0*32 + (lane>>4)*8 + i][j*16 + (lane&15)], stored at frag*512 + lane*8 + i.
// frag id within set = j*KB + k0 (KB = K/32). Layers store W' = (1-b)I + b*W.

__global__ void prep_kernel(const float* __restrict__ W0, const float* __restrict__ W1,
                            const float* __restrict__ CW, u16* __restrict__ Wfrag) {
    int f = blockIdx.x;
    int lane = threadIdx.x;  // 64
    const float* Wsrc;
    int KB, N, fl;
    float beta = -1.f;
    if (f < 64) { Wsrc = W0; KB = 8; N = 128; fl = f; }
    else if (f < 576) {
        int l = (f - 64) >> 5; fl = (f - 64) & 31;
        Wsrc = CW + (size_t)l * HH * HH; KB = 4; N = 128;
        beta = logf(0.5f / (float)(l + 1) + 1.0f);
    } else { Wsrc = W1; KB = 4; N = 64; fl = f - 576; }
    int j = fl / KB, k0 = fl % KB;
    int n = j * 16 + (lane & 15);
    u16* dst = Wfrag + (size_t)f * 512 + lane * 8;
#pragma unroll
    for (int i = 0; i < 8; ++i) {
        int k = k0 * 32 + ((lane >> 4) << 3) + i;
        float v = Wsrc[(size_t)k * N + n];
        if (beta >= 0.f) v = beta * v + ((k == n) ? (1.f - beta) : 0.f);
        dst[i] = f2bf(v);
    }
}

// ---------------- lin0: x = relu(X @ W0 + b0) -> xcur, x0 (bf16) ----------------

__global__ __launch_bounds__(256) void lin0_kernel(const float* __restrict__ X,
                                                   const u16* __restrict__ wf,
                                                   const float* __restrict__ B0,
                                                   u16* __restrict__ xcur,
                                                   u16* __restrict__ x0) {
    int lane = threadIdx.x & 63, w = threadIdx.x >> 6;
    int mb = (blockIdx.x * 4 + w) * 16;
    int r = lane & 15, g = lane >> 4;
    int arow = mb + r; if (arow >= NN) arow = NN - 1;
    const float* aprow = X + (size_t)arow * FIN + g * 8;
    const short8* bp = (const short8*)wf + lane;
    f32x4 acc[8] = {};
#pragma unroll
    for (int k0 = 0; k0 < 8; ++k0) {
        float8 af = *(const float8*)(aprow + k0 * 32);
        short8 a;
#pragma unroll
        for (int i = 0; i < 8; ++i) a[i] = (short)f2bf(af[i]);
#pragma unroll
        for (int j = 0; j < 8; ++j)
            acc[j] = __builtin_amdgcn_mfma_f32_16x16x32_bf16(a, bp[(j * 8 + k0) * 64], acc[j], 0, 0, 0);
    }
#pragma unroll
    for (int j = 0; j < 8; ++j) {
        int col = j * 16 + r;
        float b = B0[col];
#pragma unroll
        for (int reg = 0; reg < 4; ++reg) {
            int row = mb + g * 4 + reg;
            if (row < NN) {
                size_t idx = (size_t)row * HH + col;
                u16 v = f2bf(fmaxf(acc[j][reg] + b, 0.f));
                xcur[idx] = v;
                x0[idx] = v;
            }
        }
    }
}

// ---------------- SpMM + residual mix: h = 0.9*agg + 0.1*x0 ----------------
// One wave per node; lane owns bf16 feature pair. 16-deep gather unroll for MLP.

__global__ __launch_bounds__(256) void spmm_kernel(const u32* __restrict__ xcur,
                                                   const u32* __restrict__ x0,
                                                   const u32* __restrict__ csr,
                                                   const int* __restrict__ row_start,
                                                   u32* __restrict__ h) {
    int node = blockIdx.x * 4 + (threadIdx.x >> 6);
    int d2 = threadIdx.x & 63;
    if (node >= NN) return;
    int p = row_start[node], pe = row_start[node + 1];
    float acc0 = 0.f, acc1 = 0.f;
    for (; p + 16 <= pe; p += 16) {
        u32 m[16];
#pragma unroll
        for (int q = 0; q < 16; ++q) m[q] = csr[p + q];
        u32 v[16];
#pragma unroll
        for (int q = 0; q < 16; ++q) v[q] = xcur[(size_t)(m[q] >> 15) * 64 + d2];
#pragma unroll
        for (int q = 0; q < 16; ++q) {
            float w = (float)(m[q] & 0x7fffu) * (1.0f / 1048544.0f);
            acc0 += w * bf2f((u16)v[q]);
            acc1 += w * bf2f((u16)(v[q] >> 16));
        }
    }
    for (; p + 4 <= pe; p += 4) {
        u32 m[4];
#pragma unroll
        for (int q = 0; q < 4; ++q) m[q] = csr[p + q];
        u32 v[4];
#pragma unroll
        for (int q = 0; q < 4; ++q) v[q] = xcur[(size_t)(m[q] >> 15) * 64 + d2];
#pragma unroll
        for (int q = 0; q < 4; ++q) {
            float w = (float)(m[q] & 0x7fffu) * (1.0f / 1048544.0f);
            acc0 += w * bf2f((u16)v[q]);
            acc1 += w * bf2f((u16)(v[q] >> 16));
        }
    }
    for (; p < pe; ++p) {
        u32 m = csr[p];
        float w = (float)(m & 0x7fffu) * (1.0f / 1048544.0f);
        u32 v = xcur[(size_t)(m >> 15) * 64 + d2];
        acc0 += w * bf2f((u16)v);
        acc1 += w * bf2f((u16)(v >> 16));
    }
    int idx = node * 64 + d2;
    u32 xv = x0[idx];
    float r0 = 0.9f * acc0 + 0.1f * bf2f((u16)xv);
    float r1 = 0.9f * acc1 + 0.1f * bf2f((u16)(xv >> 16));
    h[idx] = pack2(r0, r1);
}

// ---------------- layer: x = relu(h @ W' + x), W' = (1-b)I + b*W ----------------

__global__ __launch_bounds__(256) void layer_kernel(const u16* __restrict__ h,
                                                    const u16* __restrict__ wf,
                                                    u16* __restrict__ x) {
    int lane = threadIdx.x & 63, w = threadIdx.x >> 6;
    int mb = (blockIdx.x * 4 + w) * 16;
    int r = lane & 15, g = lane >> 4;
    int arow = mb + r; if (arow >= NN) arow = NN - 1;
    const short8* ap = (const short8*)(h + (size_t)arow * HH) + g;
    const short8* bp = (const short8*)wf + lane;
    f32x4 acc[8] = {};
#pragma unroll
    for (int k0 = 0; k0 < 4; ++k0) {
        short8 a = ap[k0 * 4];
#pragma unroll
        for (int j = 0; j < 8; ++j)
            acc[j] = __builtin_amdgcn_mfma_f32_16x16x32_bf16(a, bp[(j * 4 + k0) * 64], acc[j], 0, 0, 0);
    }
#pragma unroll
    for (int j = 0; j < 8; ++j) {
        int col = j * 16 + r;
#pragma unroll
        for (int reg = 0; reg < 4; ++reg) {
            int row = mb + g * 4 + reg;
            if (row < NN) {
                size_t idx = (size_t)row * HH + col;
                float v = acc[j][reg] + bf2f(x[idx]);
                x[idx] = f2bf(fmaxf(v, 0.f));
            }
        }
    }
}

// ---------------- lin1: out = x @ W1 + b1 (fp32 out) ----------------

__global__ __launch_bounds__(256) void lin1_kernel(const u16* __restrict__ x,
                                                   const u16* __restrict__ wf,
                                                   const float* __restrict__ B1,
                                                   float* __restrict__ out) {
    int lane = threadIdx.x & 63, w = threadIdx.x >> 6;
    int mb = (blockIdx.x * 4 + w) * 16;
    int r = lane & 15, g = lane >> 4;
    int arow = mb + r; if (arow >= NN) arow = NN - 1;
    const short8* ap = (const short8*)(x + (size_t)arow * HH) + g;
    const short8* bp = (const short8*)wf + lane;
    f32x4 acc[4] = {};
#pragma unroll
    for (int k0 = 0; k0 < 4; ++k0) {
        short8 a = ap[k0 * 4];
#pragma unroll
        for (int j = 0; j < 4; ++j)
            acc[j] = __builtin_amdgcn_mfma_f32_16x16x32_bf16(a, bp[(j * 4 + k0) * 64], acc[j], 0, 0, 0);
    }
#pragma unroll
    for (int j = 0; j < 4; ++j) {
        int col = j * 16 + r;
        float b = B1[col];
#pragma unroll
        for (int reg = 0; reg < 4; ++reg) {
            int row = mb + g * 4 + reg;
            if (row < NN) out[(size_t)row * CC + col] = acc[j][reg] + b;
        }
    }
}

// ---------------- host ----------------

extern "C" void kernel_launch(void* const* d_in, const int* in_sizes, int n_in,
                              void* d_out, int out_size, void* d_ws, size_t ws_size,
                              hipStream_t stream) {
    const float* X  = (const float*)d_in[0];
    const int* esrc = (const int*)d_in[1];
    const int* edst = (const int*)d_in[2];
    const float* ew = (const float*)d_in[3];
    const float* W0 = (const float*)d_in[4];
    const float* B0 = (const float*)d_in[5];
    const float* W1 = (const float*)d_in[6];
    const float* B1 = (const float*)d_in[7];
    const float* CW = (const float*)d_in[8];
    float* out = (float*)d_out;

    char* p = (char*)d_ws;
    auto alloc = [&](size_t bytes) {
        char* r = p;
        p += (bytes + 255) & ~(size_t)255;
        return r;
    };
    u16* xcur      = (u16*)alloc((size_t)NN * HH * 2);
    u16* x0        = (u16*)alloc((size_t)NN * HH * 2);
    u16* hbuf      = (u16*)alloc((size_t)NN * HH * 2);
    int* row_start = (int*)alloc((size_t)(NN + 1) * 4);
    int* counts    = (int*)alloc((size_t)NN * 4);
    int* incl      = (int*)alloc((size_t)NN * 4);
    int* bsum      = (int*)alloc((size_t)512 * 4);
    int* rank      = (int*)alloc((size_t)NE * 4);
    u32* csr       = (u32*)alloc((size_t)NE * 4);
    u16* Wfrag     = (u16*)alloc((size_t)592 * 512 * 2);

    hipMemsetAsync(counts, 0, (size_t)NN * 4, stream);
    hist_kernel<<<NE / 256, 256, 0, stream>>>(edst, counts, rank);
    scanA_kernel<<<NBLK, 256, 0, stream>>>(counts, incl, bsum);
    scanB_kernel<<<1, 512, 0, stream>>>(bsum);
    scanC_kernel<<<NBLK, 256, 0, stream>>>(counts, incl, bsum, row_start);
    scatter_kernel<<<NE / 256, 256, 0, stream>>>(esrc, edst, ew, row_start, rank, csr);
    prep_kernel<<<592, 64, 0, stream>>>(W0, W1, CW, Wfrag);

    const int gemm_blocks = (NN + 63) / 64;
    lin0_kernel<<<gemm_blocks, 256, 0, stream>>>(X, Wfrag, B0, xcur, x0);

    for (int l = 0; l < NL; ++l) {
        spmm_kernel<<<(NN + 3) / 4, 256, 0, stream>>>((const u32*)xcur, (const u32*)x0,
                                                      csr, row_start, (u32*)hbuf);
        layer_kernel<<<gemm_blocks, 256, 0, stream>>>(hbuf, Wfrag + (size_t)(64 + 32 * l) * 512, xcur);
    }

    lin1_kernel<<<gemm_blocks, 256, 0, stream>>>(xcur, Wfrag + (size_t)576 * 512, B1, out);
}

// Round 6
// 2413.094 us; speedup vs baseline: 1.5608x; 1.0183x over previous
//
#include <hip/hip_runtime.h>
#include <math.h>

#define NN 100000
#define NE 3200000
#define FIN 256
#define HH 128
#define CC 64
#define NL 16
#define NBLK 391  // ceil(NN/256)

typedef unsigned short u16;
typedef unsigned int u32;
typedef short short8 __attribute__((ext_vector_type(8)));
typedef float f32x4 __attribute__((ext_vector_type(4)));
typedef float float8 __attribute__((ext_vector_type(8)));

__device__ __forceinline__ float bf2f(u16 u) {
    u32 v = ((u32)u) << 16;
    return __builtin_bit_cast(float, v);
}
__device__ __forceinline__ u16 f2bf(float f) {
    u32 x = __builtin_bit_cast(u32, f);
    u32 lsb = (x >> 16) & 1;
    x += 0x7fffu + lsb;
    return (u16)(x >> 16);
}
__device__ __forceinline__ u32 pack2(float a, float b) {
    return (u32)f2bf(a) | ((u32)f2bf(b) << 16);
}

// ---------------- CSR build ----------------
// XCD-privatized histogram: copy = blockIdx&7 (matches round-robin XCD dispatch),
// so atomic cache lines stay XCD-local. Edge e's copy = (e>>8)&7 (pure fn of e).

__global__ void hist_kernel(const int* __restrict__ edst, int* __restrict__ cp,
                            int* __restrict__ rank) {
    int e = blockIdx.x * 256 + threadIdx.x;
    if (e < NE) {
        int part = blockIdx.x & 7;
        rank[e] = atomicAdd(&cp[part * NN + edst[e]], 1);
    }
}

// cp[p][i] -> exclusive prefix over p (per node), counts[i] = total degree
__global__ __launch_bounds__(256) void combine_kernel(int* __restrict__ cp,
                                                      int* __restrict__ counts) {
    int i = blockIdx.x * 256 + threadIdx.x;
    if (i < NN) {
        int s = 0;
#pragma unroll
        for (int p = 0; p < 8; ++p) {
            int v = cp[p * NN + i];
            cp[p * NN + i] = s;
            s += v;
        }
        counts[i] = s;
    }
}

// hierarchical scan: A = per-256-block inclusive scan, B = scan of block sums, C = combine
__global__ __launch_bounds__(256) void scanA_kernel(const int* __restrict__ counts,
                                                    int* __restrict__ incl, int* __restrict__ bsum) {
    __shared__ int s[256];
    int t = threadIdx.x, i = blockIdx.x * 256 + t;
    s[t] = (i < NN) ? counts[i] : 0;
    __syncthreads();
    for (int off = 1; off < 256; off <<= 1) {
        int v = (t >= off) ? s[t - off] : 0;
        __syncthreads();
        s[t] += v;
        __syncthreads();
    }
    if (i < NN) incl[i] = s[t];
    if (t == 255) bsum[blockIdx.x] = s[255];
}

__global__ __launch_bounds__(512) void scanB_kernel(int* __restrict__ bsum) {
    __shared__ int s[512];
    int t = threadIdx.x;
    s[t] = (t < NBLK) ? bsum[t] : 0;
    __syncthreads();
    for (int off = 1; off < 512; off <<= 1) {
        int v = (t >= off) ? s[t - off] : 0;
        __syncthreads();
        s[t] += v;
        __syncthreads();
    }
    if (t < NBLK) bsum[t] = s[t];
}

__global__ __launch_bounds__(256) void scanC_kernel(const int* __restrict__ counts,
                                                    const int* __restrict__ incl,
                                                    const int* __restrict__ bsum,
                                                    int* __restrict__ row_start) {
    int t = threadIdx.x, b = blockIdx.x, i = b * 256 + t;
    if (i < NN) row_start[i] = (b ? bsum[b - 1] : 0) + incl[i] - counts[i];
    if (i == 0) row_start[NN] = NE;
}

// packed edge: u32 = (src << 15) | round(w * 32 * 32767); w in [0, 1/32)
__global__ void scatter_kernel(const int* __restrict__ esrc, const int* __restrict__ edst,
                               const float* __restrict__ ew, const int* __restrict__ row_start,
                               const int* __restrict__ rank, const int* __restrict__ cp,
                               u32* __restrict__ csr) {
    int e = blockIdx.x * 256 + threadIdx.x;
    if (e < NE) {
        int d = edst[e];
        int part = (e >> 8) & 7;
        int pos = row_start[d] + cp[part * NN + d] + rank[e];
        u32 wq = (u32)(ew[e] * 1048544.0f + 0.5f);
        if (wq > 32767u) wq = 32767u;
        csr[pos] = ((u32)esrc[e] << 15) | wq;
    }
}

// ---------------- weight fragment prep ----------------
// Fragment f of a weight set [K x N]: lane holds 8 contiguous bf16 =
// W[k0*32 + (lane>>4)*8 + i][j*16 + (lane&15)], stored at frag*512 + lane*8 + i.
// frag id within set = j*KB + k0 (KB = K/32). Layers store W' = (1-b)I + b*W.

__global__ void prep_kernel(const float* __restrict__ W0, const float* __restrict__ W1,
                            const float* __restrict__ CW, u16* __restrict__ Wfrag) {
    int f = blockIdx.x;
    int lane = threadIdx.x;  // 64
    const float* Wsrc;
    int KB, N, fl;
    float beta = -1.f;
    if (f < 64) { Wsrc = W0; KB = 8; N = 128; fl = f; }
    else if (f < 576) {
        int l = (f - 64) >> 5; fl = (f - 64) & 31;
        Wsrc = CW + (size_t)l * HH * HH; KB = 4; N = 128;
        beta = logf(0.5f / (float)(l + 1) + 1.0f);
    } else { Wsrc = W1; KB = 4; N = 64; fl = f - 576; }
    int j = fl / KB, k0 = fl % KB;
    int n = j * 16 + (lane & 15);
    u16* dst = Wfrag + (size_t)f * 512 + lane * 8;
#pragma unroll
    for (int i = 0; i < 8; ++i) {
        int k = k0 * 32 + ((lane >> 4) << 3) + i;
        float v = Wsrc[(size_t)k * N + n];
        if (beta >= 0.f) v = beta * v + ((k == n) ? (1.f - beta) : 0.f);
        dst[i] = f2bf(v);
    }
}

// ---------------- lin0: x = relu(X @ W0 + b0) -> xcur, x0 (bf16) ----------------

__global__ __launch_bounds__(256) void lin0_kernel(const float* __restrict__ X,
                                                   const u16* __restrict__ wf,
                                                   const float* __restrict__ B0,
                                                   u16* __restrict__ xcur,
                                                   u16* __restrict__ x0) {
    int lane = threadIdx.x & 63, w = threadIdx.x >> 6;
    int mb = (blockIdx.x * 4 + w) * 16;
    int r = lane & 15, g = lane >> 4;
    int arow = mb + r; if (arow >= NN) arow = NN - 1;
    const float* aprow = X + (size_t)arow * FIN + g * 8;
    const short8* bp = (const short8*)wf + lane;
    f32x4 acc[8] = {};
#pragma unroll
    for (int k0 = 0; k0 < 8; ++k0) {
        float8 af = *(const float8*)(aprow + k0 * 32);
        short8 a;
#pragma unroll
        for (int i = 0; i < 8; ++i) a[i] = (short)f2bf(af[i]);
#pragma unroll
        for (int j = 0; j < 8; ++j)
            acc[j] = __builtin_amdgcn_mfma_f32_16x16x32_bf16(a, bp[(j * 8 + k0) * 64], acc[j], 0, 0, 0);
    }
#pragma unroll
    for (int j = 0; j < 8; ++j) {
        int col = j * 16 + r;
        float b = B0[col];
#pragma unroll
        for (int reg = 0; reg < 4; ++reg) {
            int row = mb + g * 4 + reg;
            if (row < NN) {
                size_t idx = (size_t)row * HH + col;
                u16 v = f2bf(fmaxf(acc[j][reg] + b, 0.f));
                xcur[idx] = v;
                x0[idx] = v;
            }
        }
    }
}

// ---------------- fused layer: xout = relu( [0.9*SpMM(xin) + 0.1*x0] @ W' + xin ) ----------------
// 16 nodes/block (grid 6250). Gather: wave w handles nodes w*4..w*4+3 (one wave per
// node, lane owns a bf16 feature pair), 16-deep unroll; mixed h row -> swizzled LDS.
// GEMM: all 4 waves share the 16-row A tile; wave w computes column frags 2w, 2w+1.
// LDS swizzle: u16 idx ^= (row&7)<<3 -> 16B-aligned, banks spread 8-way (2-way resid, free).

__global__ __launch_bounds__(256) void fused_kernel(const u16* __restrict__ xin,
                                                    const u16* __restrict__ x0,
                                                    const u32* __restrict__ csr,
                                                    const int* __restrict__ row_start,
                                                    const u16* __restrict__ wf,
                                                    u16* __restrict__ xout) {
    __shared__ u16 hlds[16 * 128];  // 4 KB
    int t = threadIdx.x, w = t >> 6, lane = t & 63;
    int nb = blockIdx.x * 16;
    const u32* xg = (const u32*)xin;
    const u32* x0g = (const u32*)x0;

    for (int i = 0; i < 4; ++i) {
        int row = w * 4 + i;
        int node = nb + row;
        float a0 = 0.f, a1 = 0.f;
        if (node < NN) {
            int p = row_start[node], pe = row_start[node + 1];
            for (; p + 16 <= pe; p += 16) {
                u32 m[16];
#pragma unroll
                for (int q = 0; q < 16; ++q) m[q] = csr[p + q];
                u32 v[16];
#pragma unroll
                for (int q = 0; q < 16; ++q) v[q] = xg[(size_t)(m[q] >> 15) * 64 + lane];
#pragma unroll
                for (int q = 0; q < 16; ++q) {
                    float wt = (float)(m[q] & 0x7fffu) * (1.0f / 1048544.0f);
                    a0 += wt * bf2f((u16)v[q]);
                    a1 += wt * bf2f((u16)(v[q] >> 16));
                }
            }
            for (; p + 4 <= pe; p += 4) {
                u32 m[4];
#pragma unroll
                for (int q = 0; q < 4; ++q) m[q] = csr[p + q];
                u32 v[4];
#pragma unroll
                for (int q = 0; q < 4; ++q) v[q] = xg[(size_t)(m[q] >> 15) * 64 + lane];
#pragma unroll
                for (int q = 0; q < 4; ++q) {
                    float wt = (float)(m[q] & 0x7fffu) * (1.0f / 1048544.0f);
                    a0 += wt * bf2f((u16)v[q]);
                    a1 += wt * bf2f((u16)(v[q] >> 16));
                }
            }
            for (; p < pe; ++p) {
                u32 m = csr[p];
                float wt = (float)(m & 0x7fffu) * (1.0f / 1048544.0f);
                u32 v = xg[(size_t)(m >> 15) * 64 + lane];
                a0 += wt * bf2f((u16)v);
                a1 += wt * bf2f((u16)(v >> 16));
            }
            u32 xv = x0g[(size_t)node * 64 + lane];
            a0 = 0.9f * a0 + 0.1f * bf2f((u16)xv);
            a1 = 0.9f * a1 + 0.1f * bf2f((u16)(xv >> 16));
        }
        u32 idx = (u32)(row * 128 + lane * 2) ^ (u32)((row & 7) << 3);
        *(u32*)&hlds[idx] = pack2(a0, a1);
    }
    __syncthreads();

    // GEMM phase: 16x128 tile, wave w -> cols [w*32, w*32+32)
    int r = lane & 15, g = lane >> 4;
    const short8* bp = (const short8*)wf + lane;
    f32x4 acc[2] = {};
#pragma unroll
    for (int kb = 0; kb < 4; ++kb) {
        u32 idx = (u32)(r * 128 + kb * 32 + g * 8) ^ (u32)((r & 7) << 3);
        short8 a = *(const short8*)&hlds[idx];
        acc[0] = __builtin_amdgcn_mfma_f32_16x16x32_bf16(a, bp[((2 * w) * 4 + kb) * 64], acc[0], 0, 0, 0);
        acc[1] = __builtin_amdgcn_mfma_f32_16x16x32_bf16(a, bp[((2 * w + 1) * 4 + kb) * 64], acc[1], 0, 0, 0);
    }
#pragma unroll
    for (int jj = 0; jj < 2; ++jj) {
        int col = (2 * w + jj) * 16 + r;
#pragma unroll
        for (int reg = 0; reg < 4; ++reg) {
            int row = nb + g * 4 + reg;
            if (row < NN) {
                size_t idx = (size_t)row * HH + col;
                float v = acc[jj][reg] + bf2f(xin[idx]);
                xout[idx] = f2bf(fmaxf(v, 0.f));
            }
        }
    }
}

// ---------------- lin1: out = x @ W1 + b1 (fp32 out) ----------------

__global__ __launch_bounds__(256) void lin1_kernel(const u16* __restrict__ x,
                                                   const u16* __restrict__ wf,
                                                   const float* __restrict__ B1,
                                                   float* __restrict__ out) {
    int lane = threadIdx.x & 63, w = threadIdx.x >> 6;
    int mb = (blockIdx.x * 4 + w) * 16;
    int r = lane & 15, g = lane >> 4;
    int arow = mb + r; if (arow >= NN) arow = NN - 1;
    const short8* ap = (const short8*)(x + (size_t)arow * HH) + g;
    const short8* bp = (const short8*)wf + lane;
    f32x4 acc[4] = {};
#pragma unroll
    for (int k0 = 0; k0 < 4; ++k0) {
        short8 a = ap[k0 * 4];
#pragma unroll
        for (int j = 0; j < 4; ++j)
            acc[j] = __builtin_amdgcn_mfma_f32_16x16x32_bf16(a, bp[(j * 4 + k0) * 64], acc[j], 0, 0, 0);
    }
#pragma unroll
    for (int j = 0; j < 4; ++j) {
        int col = j * 16 + r;
        float b = B1[col];
#pragma unroll
        for (int reg = 0; reg < 4; ++reg) {
            int row = mb + g * 4 + reg;
            if (row < NN) out[(size_t)row * CC + col] = acc[j][reg] + b;
        }
    }
}

// ---------------- host ----------------

extern "C" void kernel_launch(void* const* d_in, const int* in_sizes, int n_in,
                              void* d_out, int out_size, void* d_ws, size_t ws_size,
                              hipStream_t stream) {
    const float* X  = (const float*)d_in[0];
    const int* esrc = (const int*)d_in[1];
    const int* edst = (const int*)d_in[2];
    const float* ew = (const float*)d_in[3];
    const float* W0 = (const float*)d_in[4];
    const float* B0 = (const float*)d_in[5];
    const float* W1 = (const float*)d_in[6];
    const float* B1 = (const float*)d_in[7];
    const float* CW = (const float*)d_in[8];
    float* out = (float*)d_out;

    char* p = (char*)d_ws;
    auto alloc = [&](size_t bytes) {
        char* r = p;
        p += (bytes + 255) & ~(size_t)255;
        return r;
    };
    u16* xbuf0     = (u16*)alloc((size_t)NN * HH * 2);
    u16* xbuf1     = (u16*)alloc((size_t)NN * HH * 2);
    u16* x0        = (u16*)alloc((size_t)NN * HH * 2);
    int* row_start = (int*)alloc((size_t)(NN + 1) * 4);
    int* counts    = (int*)alloc((size_t)NN * 4);
    int* incl      = (int*)alloc((size_t)NN * 4);
    int* bsum      = (int*)alloc((size_t)512 * 4);
    int* cp        = (int*)alloc((size_t)8 * NN * 4);
    int* rank      = (int*)alloc((size_t)NE * 4);
    u32* csr       = (u32*)alloc((size_t)NE * 4);
    u16* Wfrag     = (u16*)alloc((size_t)592 * 512 * 2);

    hipMemsetAsync(cp, 0, (size_t)8 * NN * 4, stream);
    hist_kernel<<<NE / 256, 256, 0, stream>>>(edst, cp, rank);
    combine_kernel<<<NBLK, 256, 0, stream>>>(cp, counts);
    scanA_kernel<<<NBLK, 256, 0, stream>>>(counts, incl, bsum);
    scanB_kernel<<<1, 512, 0, stream>>>(bsum);
    scanC_kernel<<<NBLK, 256, 0, stream>>>(counts, incl, bsum, row_start);
    scatter_kernel<<<NE / 256, 256, 0, stream>>>(esrc, edst, ew, row_start, rank, cp, csr);
    prep_kernel<<<592, 64, 0, stream>>>(W0, W1, CW, Wfrag);

    lin0_kernel<<<(NN + 63) / 64, 256, 0, stream>>>(X, Wfrag, B0, xbuf0, x0);

    u16* bufs[2] = { xbuf0, xbuf1 };
    for (int l = 0; l < NL; ++l) {
        fused_kernel<<<(NN + 15) / 16, 256, 0, stream>>>(bufs[l & 1], x0, csr, row_start,
                                                         Wfrag + (size_t)(64 + 32 * l) * 512,
                                                         bufs[(l + 1) & 1]);
    }

    lin1_kernel<<<(NN + 63) / 64, 256, 0, stream>>>(bufs[0], Wfrag + (size_t)576 * 512, B1, out);
}